// Round 8
// baseline (162.221 us; speedup 1.0000x reference)
//
#include <hip/hip_runtime.h>

typedef __bf16 bf16;
using short8 = __attribute__((ext_vector_type(8))) __bf16;
using f32x4  = __attribute__((ext_vector_type(4))) float;

#define N_TOK 4128
#define QD    320
#define DH    40
#define W_VIS 4096
#define SPLITS 8
#define N_SP  4224
#define PROWS 4160    /* opart rows per (split,head); rows >=4160 are pure pad, skipped */
#define BSTRIDE 344   /* LDS B-stage stride: 16B-aligned rows, 2-way (free) frag reads */

#if __has_builtin(__builtin_amdgcn_exp2f)
#define EXP2F(x) __builtin_amdgcn_exp2f(x)
#else
#define EXP2F(x) exp2f(x)
#endif

__device__ __forceinline__ float loadS(const void* b, long i, bool isbf) {
  return isbf ? (float)((const bf16*)b)[i] : ((const float*)b)[i];
}
__device__ __forceinline__ unsigned short bfbits(float x) {
  bf16 h = (bf16)x;
  return __builtin_bit_cast(unsigned short, h);
}

// per-block dtype sniff: att is {0,1}; as fp32 its even halfwords are all 0;
// as bf16 ~15% are 0x3F80. 256 samples -> P(miss) ~ 0.85^256 ~ 4e-19.
__device__ __forceinline__ bool blk_sniff(const unsigned short* att_h, int nthr) {
  __shared__ int s;
  if (threadIdx.x == 0) s = 0;
  __syncthreads();
  int step = 8192 / nthr;
  if (att_h[threadIdx.x * step] != 0) atomicOr(&s, 1);
  __syncthreads();
  return s != 0;
}

// ---------- one-shot dtype normalization: x,Wq,Wk,Wv,Wo -> bf16; bo -> f32.
// Removes ALL per-use fp32->bf16 conversion VALU from the GEMM hot loops. ----------
#define XCH  165120   /* 4128*320/8 */
#define WCH  12800    /* 320*320/8 */
__global__ __launch_bounds__(256) void cvt_kernel(
    const void* __restrict__ x, const void* __restrict__ Wq, const void* __restrict__ Wk,
    const void* __restrict__ Wv, const void* __restrict__ Wo, const void* __restrict__ bo,
    const void* __restrict__ att,
    bf16* __restrict__ xb, bf16* __restrict__ wqb, bf16* __restrict__ wkb,
    bf16* __restrict__ wvb, bf16* __restrict__ wob, float* __restrict__ bof) {
  bool isbf = blk_sniff((const unsigned short*)att, 256);
  int c = blockIdx.x * 256 + threadIdx.x;
  const void* src; bf16* dst; long off;
  if (c < XCH)               { src = x;  dst = xb;  off = c; }
  else if (c < XCH + WCH)    { src = Wq; dst = wqb; off = c - XCH; }
  else if (c < XCH + 2*WCH)  { src = Wk; dst = wkb; off = c - XCH - WCH; }
  else if (c < XCH + 3*WCH)  { src = Wv; dst = wvb; off = c - XCH - 2*WCH; }
  else if (c < XCH + 4*WCH)  { src = Wo; dst = wob; off = c - XCH - 3*WCH; }
  else if (c < XCH + 4*WCH + 40) {
    long o = (long)(c - XCH - 4*WCH) * 8;
#pragma unroll
    for (int j = 0; j < 8; ++j) bof[o + j] = loadS(bo, o + j, isbf);
    return;
  } else return;
  long e = off * 8;
  if (isbf) {
    *(short8*)(dst + e) = *(const short8*)((const bf16*)src + e);
  } else {
    const float* f = (const float*)src + e;
    float4 a = *(const float4*)f, b4 = *(const float4*)(f + 4);
    union { short8 v; unsigned short u[8]; } u;
    u.u[0] = bfbits(a.x);  u.u[1] = bfbits(a.y);  u.u[2] = bfbits(a.z);  u.u[3] = bfbits(a.w);
    u.u[4] = bfbits(b4.x); u.u[5] = bfbits(b4.y); u.u[6] = bfbits(b4.z); u.u[7] = bfbits(b4.w);
    *(short8*)(dst + e) = u.v;
  }
}

// ---------- mega QKV: masks+ones (by==15) | pure-bf16 GEMM with LDS-staged B,
// epilogue writes q row-major + kswz/vswz fragment layouts straight from LDS C ----------
__global__ __launch_bounds__(256) void qkv_mega(
    const bf16* __restrict__ x, const void* __restrict__ att,
    const bf16* __restrict__ Wq, const bf16* __restrict__ Wk, const bf16* __restrict__ Wv,
    bf16* __restrict__ q, bf16* __restrict__ kswz, bf16* __restrict__ vswz,
    unsigned short* __restrict__ awA, unsigned short* __restrict__ bwB) {
  bool isbf = blk_sniff((const unsigned short*)att, 256);
  if (blockIdx.y == 15) {      // ---- util slice: mask words + vswz d=40..47 ones/zeros
    int flat = blockIdx.x * 256 + threadIdx.x;
    if (flat < N_SP) {
      int t = flat;
      unsigned int Aw = 0u, Bw = 0u;
      if (t < N_TOK) {
        unsigned int b9 = 0u; bool forced = false;
        if (t < W_VIS) {
#pragma unroll
          for (int o = 0; o < 8; ++o)
            if (loadS(att, o * W_VIS + t, isbf) != 0.0f) b9 |= (1u << o);
        } else {
          int g = t - W_VIS;
          int rep = g >> 3, oo = g & 7;
          forced = (rep == 1 || rep == 2);
          b9 = 0x100u | (forced ? 0u : (1u << oo));
        }
        Aw = b9 | (forced ? 0x200u : 0u) | 0x400u;
        Bw = b9 | (forced ? 0x400u : 0u) | 0x200u;
      }
      awA[t] = (unsigned short)Aw;
      bwB[t] = (unsigned short)Bw;
    } else if (flat - N_SP < 8320) {
      int idx = flat - N_SP;
#pragma unroll
      for (int m = 0; m < 4; ++m) {
        int t = idx * 4 + m;           // 0..33279
        int li8 = t & 7; int t2 = t >> 3;
        int q2 = t2 & 3; t2 >>= 2;
        int ksv = t2 & 1; t2 >>= 1;
        int kt = t2 % 65, h = t2 / 65;
        bf16 val = (li8 == 0) ? (bf16)1.0f : (bf16)0.0f;   // d=40 ones (l via MFMA)
        short8 v8 = {val, val, val, val, val, val, val, val};
        long base = (((long)h * 65 + kt) * 6 + ksv * 3 + 2) * 512;
        *(short8*)(vswz + base + (q2 * 16 + 8 + li8) * 8) = v8;
      }
    }
    return;
  }
  __shared__ unsigned short lbuf[64 * BSTRIDE];   // B-stage; aliased as C-tile later
  int m0 = blockIdx.x * 64;
  int ng = blockIdx.y * 64;
  int wsel = ng / 320;                 // 0=q 1=k 2=v
  int n_in = ng % 320;
  const bf16* W = wsel == 0 ? Wq : wsel == 1 ? Wk : Wv;
  // ---- stage B: W[k][n] -> lbuf[n_rel][k] (coalesced ushort4 reads, b16 transpose)
  {
    int krow0 = threadIdx.x >> 2;
    int c16 = (threadIdx.x & 3) * 16;
#pragma unroll
    for (int it = 0; it < 5; ++it) {
      int kk = it * 64 + krow0;
      const unsigned short* wp = (const unsigned short*)W + (long)kk * QD + n_in + c16;
#pragma unroll
      for (int j4 = 0; j4 < 4; ++j4) {
        ushort4 u4 = *(const ushort4*)(wp + j4 * 4);
        lbuf[(c16 + j4 * 4 + 0) * BSTRIDE + kk] = u4.x;
        lbuf[(c16 + j4 * 4 + 1) * BSTRIDE + kk] = u4.y;
        lbuf[(c16 + j4 * 4 + 2) * BSTRIDE + kk] = u4.z;
        lbuf[(c16 + j4 * 4 + 3) * BSTRIDE + kk] = u4.w;
      }
    }
  }
  __syncthreads();
  int wv = threadIdx.x >> 6, lane = threadIdx.x & 63;
  int quad = lane >> 4, li = lane & 15;
  int wm = wv >> 1, wn = wv & 1;
  f32x4 acc[2][2];
#pragma unroll
  for (int a = 0; a < 2; a++)
#pragma unroll
    for (int b = 0; b < 2; b++) acc[a][b] = (f32x4){0.f, 0.f, 0.f, 0.f};
#pragma unroll
  for (int ks = 0; ks < 10; ++ks) {
    short8 af[2], bfrag[2];
#pragma unroll
    for (int mt = 0; mt < 2; ++mt) {
      long r = m0 + wm * 32 + mt * 16 + li;
      if (r > N_TOK - 1) r = N_TOK - 1;
      af[mt] = *(const short8*)(x + r * QD + ks * 32 + quad * 8);
    }
#pragma unroll
    for (int nt = 0; nt < 2; ++nt) {
      int nr = wn * 32 + nt * 16 + li;
      bfrag[nt] = *(const short8*)&lbuf[nr * BSTRIDE + ks * 32 + quad * 8];
    }
#pragma unroll
    for (int mt = 0; mt < 2; ++mt)
#pragma unroll
      for (int nt = 0; nt < 2; ++nt)
        acc[mt][nt] = __builtin_amdgcn_mfma_f32_16x16x32_bf16(af[mt], bfrag[nt], acc[mt][nt], 0, 0, 0);
  }
  __syncthreads();                     // done reading lbuf as B
  unsigned short (*ct)[68] = (unsigned short(*)[68])lbuf;   // alias as C-tile
  const float qs = (wsel == 0) ? 0.15811388300841898f * 1.4426950408889634f : 1.0f;
#pragma unroll
  for (int mt = 0; mt < 2; ++mt)
#pragma unroll
    for (int nt = 0; nt < 2; ++nt)
#pragma unroll
      for (int r = 0; r < 4; ++r)
        ct[wm * 32 + mt * 16 + quad * 4 + r][wn * 32 + nt * 16 + li] =
            bfbits(acc[mt][nt][r] * qs);
  __syncthreads();
  int kt = m0 >> 6;
  if (wsel == 0) {                     // q row-major [h][tok][40]
    int row = threadIdx.x >> 2, c4 = threadIdx.x & 3;
    int grow = m0 + row;
    if (grow < N_TOK) {
#pragma unroll
      for (int i = 0; i < 4; ++i) {
        int cg = c4 + i * 4;           // 4-col chunk; 4|40 -> never crosses a head
        int col = n_in + cg * 4;
        int h = col / DH, d = col % DH;
        ushort4 pk = *(const ushort4*)&ct[row][cg * 4];
        *(ushort4*)(q + (long)h * N_TOK * DH + (long)grow * DH + d) = pk;
      }
    }
  } else if (wsel == 1) {              // K fragment layout (8-d runs never cross 64-col tile)
#pragma unroll
    for (int rep = 0; rep < 2; ++rep) {
      int u = threadIdx.x + rep * 256;
      int row = u >> 3, c8 = (u & 7) * 8;
      int gcol = n_in + c8;
      int h = gcol / DH, d0 = gcol % DH;          // d0 in {0,8,16,24,32}
      int li2 = row & 15, nt2 = row >> 4;
      long base = (((long)h * 65 + kt) * 4 + nt2) * 640 +
                  (d0 < 32 ? ((d0 >> 3) * 16 + li2) * 8 : 512 + li2 * 8);
      ushort4 a = *(const ushort4*)&ct[row][c8];
      ushort4 b = *(const ushort4*)&ct[row][c8 + 4];
      *(ushort4*)(kswz + base) = a;
      *(ushort4*)(kswz + base + 4) = b;
    }
  } else {                             // V fragment layout (8-tok octets, column gather)
#pragma unroll
    for (int rep = 0; rep < 2; ++rep) {
      int u = threadIdx.x + rep * 256;
      int g = u & 7, dcol = u >> 3;
      int gcol = n_in + dcol;
      int h = gcol / DH, d = gcol % DH;
      int dt = d >> 4, li2 = d & 15, ksv = g >> 2, q2 = g & 3;
      union { unsigned short e[8]; ushort4 v[2]; } o;
#pragma unroll
      for (int j = 0; j < 8; ++j) o.e[j] = ct[g * 8 + j][dcol];
      long base = (((long)h * 65 + kt) * 6 + ksv * 3 + dt) * 512 + (q2 * 16 + li2) * 8;
      *(ushort4*)(vswz + base) = o.v[0];
      *(ushort4*)(vswz + base + 4) = o.v[1];
    }
  }
}

// ---------- split-K flash attention: static-max softmax, 32 q-rows/wave,
// 4-wave blocks, single P buffer, SPLITS=8. Proven R0/R7 layout (0 conflicts).
// Round-8: intra-iteration phase split. exp factorizes by key-half: PV ksv=0
// reads only pbuf cols 0..31 (written by nt=0,1). Order exp01 -> PV0 ->
// exp23 -> PV1 lets PV0's matrix-pipe MFMAs overlap exp23's VALU (independent
// data, separate pipes) and halves each lgkm drain. Pure reorder, no new live
// state (R6's spill was the 128-cap, not the structure). T5 setprio(1) wraps
// MFMA clusters (m191: +4-7% on free-drifting attn waves; no barrier in loop).
__global__ __launch_bounds__(256, 3) void attn_kernel(
    const bf16* __restrict__ qg, const bf16* __restrict__ kswz, const bf16* __restrict__ vswz,
    const unsigned short* __restrict__ awA, const unsigned short* __restrict__ bwB,
    float* __restrict__ opart, float* __restrict__ lpart) {
  __shared__ unsigned short pbuf[4][32][68];   // wave, row, col (single buffer)
  int bid = blockIdx.x;
  int h = bid & 7;
  int sp = (bid >> 3) & 7;             // 0..7
  int qt = bid >> 6;                   // 0..32 (128 q-rows per block)
  int kt0 = (sp * 65) >> 3;
  int kt1 = ((sp + 1) * 65) >> 3;
  int wv = threadIdx.x >> 6, lane = threadIdx.x & 63;
  int quad = lane >> 4, li = lane & 15;
  const bf16* qh = qg + h * (N_TOK * DH);
  const bf16* kz = kswz + (long)h * 65 * 2560;
  const bf16* vz = vswz + (long)h * 65 * 3072;

  int qrow_base = qt * 128 + wv * 32;  // up to 4223 < N_SP (awA padded)
  short8 qa0[2], qa1[2];
  unsigned int aw[2][4]; int qi[2][4];
#pragma unroll
  for (int mt = 0; mt < 2; ++mt) {
    int qr = qrow_base + mt * 16 + li; if (qr > N_TOK - 1) qr = N_TOK - 1;
    qa0[mt] = *(const short8*)(qh + qr * DH + quad * 8);
    qa1[mt] = (quad == 0) ? *(const short8*)(qh + qr * DH + 32) : (short8)(__bf16)0.0f;
#pragma unroll
    for (int r = 0; r < 4; ++r) {
      qi[mt][r] = qrow_base + mt * 16 + quad * 4 + r;
      aw[mt][r] = awA[qi[mt][r]];      // padded rows -> 0 -> fully masked -> o=l=0
    }
  }

  f32x4 o[2][3];
#pragma unroll
  for (int mt = 0; mt < 2; ++mt)
#pragma unroll
    for (int d = 0; d < 3; ++d) o[mt][d] = (f32x4){0.f, 0.f, 0.f, 0.f};
  const f32x4 cm8 = (f32x4){-8.f, -8.f, -8.f, -8.f};   // static softmax shift
  int dkt = qrow_base >> 6;            // the single ktile containing this wave's diagonal

#define SOFTMAX_HALF(NT0, DIAG)                                              \
  _Pragma("unroll")                                                          \
  for (int mt = 0; mt < 2; ++mt)                                             \
    _Pragma("unroll")                                                        \
    for (int nt = NT0; nt < NT0 + 2; ++nt)                                   \
      _Pragma("unroll")                                                      \
      for (int r = 0; r < 4; ++r) {                                          \
        bool kp = ((aw[mt][r] & bw[nt]) != 0u) ||                            \
                  (DIAG && qi[mt][r] == (kt * 64 + nt * 16 + li));           \
        float p = EXP2F(kp ? s[mt][nt][r] : -1e5f);                          \
        pbuf[wv][mt * 16 + quad * 4 + r][nt * 16 + li] =                     \
            (unsigned short)(__builtin_bit_cast(unsigned int, p) >> 16);     \
      }

#define PV_HALF(KSV, VB)                                                     \
  {                                                                          \
    union { short8 v; ushort4 u[2]; } fp[2];                                 \
    _Pragma("unroll")                                                        \
    for (int mt = 0; mt < 2; ++mt) {                                         \
      fp[mt].u[0] = *(const ushort4*)&pbuf[wv][mt * 16 + li][(KSV) * 32 + quad * 8];     \
      fp[mt].u[1] = *(const ushort4*)&pbuf[wv][mt * 16 + li][(KSV) * 32 + quad * 8 + 4]; \
    }                                                                        \
    __builtin_amdgcn_s_setprio(1);                                           \
    _Pragma("unroll")                                                        \
    for (int dt = 0; dt < 3; ++dt) {                                         \
      o[0][dt] = __builtin_amdgcn_mfma_f32_16x16x32_bf16(fp[0].v, VB[dt], o[0][dt], 0, 0, 0); \
      o[1][dt] = __builtin_amdgcn_mfma_f32_16x16x32_bf16(fp[1].v, VB[dt], o[1][dt], 0, 0, 0); \
    }                                                                        \
    __builtin_amdgcn_s_setprio(0);                                           \
  }

  for (int kt = kt0; kt < kt1; ++kt) {
    const bf16* kb_base = kz + (long)kt * 2560;
    f32x4 s[2][4];
    unsigned int bw[4];
    __builtin_amdgcn_s_setprio(1);
#pragma unroll
    for (int nt = 0; nt < 4; ++nt) {
      bw[nt] = bwB[kt * 64 + nt * 16 + li];
      short8 kb0 = *(const short8*)(kb_base + nt * 640 + lane * 8);       // coalesced 1KB
      short8 kb1 = (quad == 0) ? *(const short8*)(kb_base + nt * 640 + 512 + li * 8)
                               : (short8)(__bf16)0.0f;
      s[0][nt] = __builtin_amdgcn_mfma_f32_16x16x32_bf16(qa0[0], kb0, cm8, 0, 0, 0);
      s[0][nt] = __builtin_amdgcn_mfma_f32_16x16x32_bf16(qa1[0], kb1, s[0][nt], 0, 0, 0);
      s[1][nt] = __builtin_amdgcn_mfma_f32_16x16x32_bf16(qa0[1], kb0, cm8, 0, 0, 0);
      s[1][nt] = __builtin_amdgcn_mfma_f32_16x16x32_bf16(qa1[1], kb1, s[1][nt], 0, 0, 0);
    }
    __builtin_amdgcn_s_setprio(0);
    // V fragments (independent of P) issued before the exp phase
    short8 vb0[3], vb1[3];
#pragma unroll
    for (int dt = 0; dt < 3; ++dt) {
      vb0[dt] = *(const short8*)(vz + ((long)kt * 6 + dt) * 512 + lane * 8);
      vb1[dt] = *(const short8*)(vz + ((long)kt * 6 + 3 + dt) * 512 + lane * 8);
    }
    // phase-split: exp keys 0..31 -> PV ksv0 (MFMA) overlaps exp keys 32..63 (VALU)
    if (kt == dkt) { SOFTMAX_HALF(0, true) } else { SOFTMAX_HALF(0, false) }
    PV_HALF(0, vb0)
    if (kt == dkt) { SOFTMAX_HALF(2, true) } else { SOFTMAX_HALF(2, false) }
    PV_HALF(1, vb1)
  }
#undef SOFTMAX_HALF
#undef PV_HALF

  long pb2 = (long)(sp * 8 + h) * PROWS;
#pragma unroll
  for (int mt = 0; mt < 2; ++mt) {
#pragma unroll
    for (int dt = 0; dt < 3; ++dt) {
      int d = dt * 16 + li;
      if (d < DH) {
#pragma unroll
        for (int r = 0; r < 4; ++r)
          if (qi[mt][r] < PROWS) opart[(pb2 + qi[mt][r]) * DH + d] = o[mt][dt][r];
      }
    }
    if (li == 8) {
#pragma unroll
      for (int r = 0; r < 4; ++r)
        if (qi[mt][r] < PROWS) lpart[pb2 + qi[mt][r]] = o[mt][2][r];
    }
  }
}

// ---------- combine partials across splits (equal weights), float4-vectorized ----------
__global__ __launch_bounds__(256) void combine_kernel(
    const float* __restrict__ opart, const float* __restrict__ lpart,
    bf16* __restrict__ attn) {
  int id = blockIdx.x * 256 + threadIdx.x;   // (h, row, d4): 8*4128*10
  if (id >= 8 * N_TOK * 10) return;
  int d4 = id % 10;
  int rw = (id / 10) % N_TOK;
  int h = id / (10 * N_TOK);
  float4 osum = make_float4(0.f, 0.f, 0.f, 0.f);
  float lsum = 0.f;
#pragma unroll
  for (int s = 0; s < SPLITS; ++s) {
    long rb = (long)(s * 8 + h) * PROWS + rw;
    float4 ov = *(const float4*)(opart + rb * DH + d4 * 4);
    osum.x += ov.x; osum.y += ov.y; osum.z += ov.z; osum.w += ov.w;
    lsum += lpart[rb];
  }
  float rl = 1.0f / fmaxf(lsum, 1e-30f);
  union { short4 s4; unsigned short hh[4]; } u;
  u.hh[0] = bfbits(osum.x * rl); u.hh[1] = bfbits(osum.y * rl);
  u.hh[2] = bfbits(osum.z * rl); u.hh[3] = bfbits(osum.w * rl);
  *(short4*)(attn + rw * QD + h * DH + d4 * 4) = u.s4;
}

// ---------- output projection + bias (pure-bf16 staging; out dtype via sniff) ----------
__global__ __launch_bounds__(256) void gemm_out(
    const bf16* __restrict__ A, const bf16* __restrict__ Wo,
    const float* __restrict__ bias, const void* __restrict__ att,
    void* __restrict__ out) {
  bool isbf = blk_sniff((const unsigned short*)att, 256);
  __shared__ unsigned short lbuf[64 * BSTRIDE];
  int m0 = blockIdx.x * 64;
  int n0 = blockIdx.y * 64;
  {
    int krow0 = threadIdx.x >> 2;
    int c16 = (threadIdx.x & 3) * 16;
#pragma unroll
    for (int it = 0; it < 5; ++it) {
      int kk = it * 64 + krow0;
      const unsigned short* wp = (const unsigned short*)Wo + (long)kk * QD + n0 + c16;
#pragma unroll
      for (int j4 = 0; j4 < 4; ++j4) {
        ushort4 u4 = *(const ushort4*)(wp + j4 * 4);
        lbuf[(c16 + j4 * 4 + 0) * BSTRIDE + kk] = u4.x;
        lbuf[(c16 + j4 * 4 + 1) * BSTRIDE + kk] = u4.y;
        lbuf[(c16 + j4 * 4 + 2) * BSTRIDE + kk] = u4.z;
        lbuf[(c16 + j4 * 4 + 3) * BSTRIDE + kk] = u4.w;
      }
    }
  }
  __syncthreads();
  int wv = threadIdx.x >> 6, lane = threadIdx.x & 63;
  int quad = lane >> 4, li = lane & 15;
  int wm = wv >> 1, wn = wv & 1;
  f32x4 acc[2][2];
#pragma unroll
  for (int a = 0; a < 2; a++)
#pragma unroll
    for (int b = 0; b < 2; b++) acc[a][b] = (f32x4){0.f, 0.f, 0.f, 0.f};
#pragma unroll
  for (int ks = 0; ks < 10; ++ks) {
    short8 af[2], bfrag[2];
#pragma unroll
    for (int mt = 0; mt < 2; ++mt) {
      int r = m0 + wm * 32 + mt * 16 + li;
      r = r < N_TOK ? r : N_TOK - 1;
      af[mt] = *(const short8*)(A + r * QD + ks * 32 + quad * 8);
    }
#pragma unroll
    for (int nt = 0; nt < 2; ++nt) {
      int nr = wn * 32 + nt * 16 + li;
      bfrag[nt] = *(const short8*)&lbuf[nr * BSTRIDE + ks * 32 + quad * 8];
    }
#pragma unroll
    for (int mt = 0; mt < 2; ++mt)
#pragma unroll
      for (int nt = 0; nt < 2; ++nt)
        acc[mt][nt] = __builtin_amdgcn_mfma_f32_16x16x32_bf16(af[mt], bfrag[nt], acc[mt][nt], 0, 0, 0);
  }
#pragma unroll
  for (int mt = 0; mt < 2; ++mt)
#pragma unroll
    for (int nt = 0; nt < 2; ++nt)
#pragma unroll
      for (int r = 0; r < 4; ++r) {
        int row = m0 + wm * 32 + mt * 16 + quad * 4 + r;
        if (row >= N_TOK) continue;
        int col = n0 + wn * 32 + nt * 16 + li;
        float val = acc[mt][nt][r] + bias[col];
        if (isbf) ((bf16*)out)[row * QD + col] = (bf16)val;
        else      ((float*)out)[row * QD + col] = val;
      }
}

extern "C" void kernel_launch(void* const* d_in, const int* in_sizes, int n_in,
                              void* d_out, int out_size, void* d_ws, size_t ws_size,
                              hipStream_t stream) {
  (void)in_sizes; (void)n_in; (void)out_size; (void)ws_size;
  const void* x   = d_in[0];
  const void* att = d_in[1];
  const void* Wq  = d_in[2];
  const void* Wk  = d_in[3];
  const void* Wv  = d_in[4];
  const void* Wo  = d_in[5];
  const void* bo  = d_in[6];
  char* ws = (char*)d_ws;
  unsigned short* awA = (unsigned short*)(ws + 0);        // 8448
  unsigned short* bwB = (unsigned short*)(ws + 8704);     // 8448
  bf16* qb    = (bf16*)(ws + 17408);                      // 2641920
  bf16* kswz  = (bf16*)(ws + 2659328);                    // 2662400
  bf16* vswz  = (bf16*)(ws + 5321728);                    // 3194880
  bf16* attnb = (bf16*)(ws + 8516608);                    // 2641920
  float* opart = (float*)(ws + 11158528);                 // 64*4160*40*4 = 42598400
  float* lpart = (float*)(ws + 53756928);                 // 64*4160*4 = 1064960 -> 54821888
  bf16* wob   = (bf16*)(ws + 54821888);                   // 204800 -> 55026688
  float* bof  = (float*)(ws + 55026688);                  // 1280 -> 55027968 (< old 55493632 peak)
  // xb/wq/wk/wv overlap opart (dead before attn_kernel writes opart):
  bf16* xb    = (bf16*)(ws + 11158528);                   // 2641920
  bf16* wqb   = (bf16*)(ws + 13800448);                   // 204800
  bf16* wkb   = (bf16*)(ws + 14005248);                   // 204800
  bf16* wvb   = (bf16*)(ws + 14210048);                   // 204800 -> 14414848

  cvt_kernel<<<(XCH + 4*WCH + 40 + 255) / 256, 256, 0, stream>>>(
      x, Wq, Wk, Wv, Wo, bo, att, xb, wqb, wkb, wvb, wob, bof);
  dim3 g1(65, 16);   // by 0..14 = GEMM tiles, by 15 = masks + vswz ones
  qkv_mega<<<g1, 256, 0, stream>>>(xb, att, wqb, wkb, wvb, qb, kswz, vswz, awA, bwB);
  attn_kernel<<<33 * SPLITS * 8, 256, 0, stream>>>(qb, kswz, vswz, awA, bwB, opart, lpart);
  combine_kernel<<<(8 * N_TOK * 10 + 255) / 256, 256, 0, stream>>>(opart, lpart, attnb);
  dim3 g2(65, 5);
  gemm_out<<<g2, 256, 0, stream>>>(attnb, wob, bof, att, d_out);
}

// Round 9
// 156.465 us; speedup vs baseline: 1.0368x; 1.0368x over previous
//
#include <hip/hip_runtime.h>

typedef __bf16 bf16;
using short8 = __attribute__((ext_vector_type(8))) __bf16;
using f32x4  = __attribute__((ext_vector_type(4))) float;

#define N_TOK 4128
#define QD    320
#define DH    40
#define W_VIS 4096
#define SPLITS 8
#define N_SP  4224
#define PROWS 4160    /* opart rows per (split,head); rows >=4160 are pure pad, skipped */
#define BSTRIDE 344   /* LDS B-stage stride: 16B-aligned rows, 2-way (free) frag reads */

#if __has_builtin(__builtin_amdgcn_exp2f)
#define EXP2F(x) __builtin_amdgcn_exp2f(x)
#else
#define EXP2F(x) exp2f(x)
#endif

__device__ __forceinline__ float loadS(const void* b, long i, bool isbf) {
  return isbf ? (float)((const bf16*)b)[i] : ((const float*)b)[i];
}
__device__ __forceinline__ unsigned short bfbits(float x) {
  bf16 h = (bf16)x;
  return __builtin_bit_cast(unsigned short, h);
}

// per-block dtype sniff: att is {0,1}; as fp32 its even halfwords are all 0;
// as bf16 ~15% are 0x3F80. 256 samples -> P(miss) ~ 0.85^256 ~ 4e-19.
__device__ __forceinline__ bool blk_sniff(const unsigned short* att_h, int nthr) {
  __shared__ int s;
  if (threadIdx.x == 0) s = 0;
  __syncthreads();
  int step = 8192 / nthr;
  if (att_h[threadIdx.x * step] != 0) atomicOr(&s, 1);
  __syncthreads();
  return s != 0;
}

// ---------- one-shot dtype normalization: x,Wq,Wk,Wv,Wo -> bf16; bo -> f32.
// Removes ALL per-use fp32->bf16 conversion VALU from the GEMM hot loops. ----------
#define XCH  165120   /* 4128*320/8 */
#define WCH  12800    /* 320*320/8 */
__global__ __launch_bounds__(256) void cvt_kernel(
    const void* __restrict__ x, const void* __restrict__ Wq, const void* __restrict__ Wk,
    const void* __restrict__ Wv, const void* __restrict__ Wo, const void* __restrict__ bo,
    const void* __restrict__ att,
    bf16* __restrict__ xb, bf16* __restrict__ wqb, bf16* __restrict__ wkb,
    bf16* __restrict__ wvb, bf16* __restrict__ wob, float* __restrict__ bof) {
  bool isbf = blk_sniff((const unsigned short*)att, 256);
  int c = blockIdx.x * 256 + threadIdx.x;
  const void* src; bf16* dst; long off;
  if (c < XCH)               { src = x;  dst = xb;  off = c; }
  else if (c < XCH + WCH)    { src = Wq; dst = wqb; off = c - XCH; }
  else if (c < XCH + 2*WCH)  { src = Wk; dst = wkb; off = c - XCH - WCH; }
  else if (c < XCH + 3*WCH)  { src = Wv; dst = wvb; off = c - XCH - 2*WCH; }
  else if (c < XCH + 4*WCH)  { src = Wo; dst = wob; off = c - XCH - 3*WCH; }
  else if (c < XCH + 4*WCH + 40) {
    long o = (long)(c - XCH - 4*WCH) * 8;
#pragma unroll
    for (int j = 0; j < 8; ++j) bof[o + j] = loadS(bo, o + j, isbf);
    return;
  } else return;
  long e = off * 8;
  if (isbf) {
    *(short8*)(dst + e) = *(const short8*)((const bf16*)src + e);
  } else {
    const float* f = (const float*)src + e;
    float4 a = *(const float4*)f, b4 = *(const float4*)(f + 4);
    union { short8 v; unsigned short u[8]; } u;
    u.u[0] = bfbits(a.x);  u.u[1] = bfbits(a.y);  u.u[2] = bfbits(a.z);  u.u[3] = bfbits(a.w);
    u.u[4] = bfbits(b4.x); u.u[5] = bfbits(b4.y); u.u[6] = bfbits(b4.z); u.u[7] = bfbits(b4.w);
    *(short8*)(dst + e) = u.v;
  }
}

// ---------- mega QKV: masks+ones (by==15) | pure-bf16 GEMM with LDS-staged B,
// epilogue writes q row-major + kswz/vswz fragment layouts straight from LDS C ----------
__global__ __launch_bounds__(256) void qkv_mega(
    const bf16* __restrict__ x, const void* __restrict__ att,
    const bf16* __restrict__ Wq, const bf16* __restrict__ Wk, const bf16* __restrict__ Wv,
    bf16* __restrict__ q, bf16* __restrict__ kswz, bf16* __restrict__ vswz,
    unsigned short* __restrict__ awA, unsigned short* __restrict__ bwB) {
  bool isbf = blk_sniff((const unsigned short*)att, 256);
  if (blockIdx.y == 15) {      // ---- util slice: mask words + vswz d=40..47 ones/zeros
    int flat = blockIdx.x * 256 + threadIdx.x;
    if (flat < N_SP) {
      int t = flat;
      unsigned int Aw = 0u, Bw = 0u;
      if (t < N_TOK) {
        unsigned int b9 = 0u; bool forced = false;
        if (t < W_VIS) {
#pragma unroll
          for (int o = 0; o < 8; ++o)
            if (loadS(att, o * W_VIS + t, isbf) != 0.0f) b9 |= (1u << o);
        } else {
          int g = t - W_VIS;
          int rep = g >> 3, oo = g & 7;
          forced = (rep == 1 || rep == 2);
          b9 = 0x100u | (forced ? 0u : (1u << oo));
        }
        Aw = b9 | (forced ? 0x200u : 0u) | 0x400u;
        Bw = b9 | (forced ? 0x400u : 0u) | 0x200u;
      }
      awA[t] = (unsigned short)Aw;
      bwB[t] = (unsigned short)Bw;
    } else if (flat - N_SP < 8320) {
      int idx = flat - N_SP;
#pragma unroll
      for (int m = 0; m < 4; ++m) {
        int t = idx * 4 + m;           // 0..33279
        int li8 = t & 7; int t2 = t >> 3;
        int q2 = t2 & 3; t2 >>= 2;
        int ksv = t2 & 1; t2 >>= 1;
        int kt = t2 % 65, h = t2 / 65;
        bf16 val = (li8 == 0) ? (bf16)1.0f : (bf16)0.0f;   // d=40 ones (l via MFMA)
        short8 v8 = {val, val, val, val, val, val, val, val};
        long base = (((long)h * 65 + kt) * 6 + ksv * 3 + 2) * 512;
        *(short8*)(vswz + base + (q2 * 16 + 8 + li8) * 8) = v8;
      }
    }
    return;
  }
  __shared__ unsigned short lbuf[64 * BSTRIDE];   // B-stage; aliased as C-tile later
  int m0 = blockIdx.x * 64;
  int ng = blockIdx.y * 64;
  int wsel = ng / 320;                 // 0=q 1=k 2=v
  int n_in = ng % 320;
  const bf16* W = wsel == 0 ? Wq : wsel == 1 ? Wk : Wv;
  // ---- stage B: W[k][n] -> lbuf[n_rel][k] (coalesced ushort4 reads, b16 transpose)
  {
    int krow0 = threadIdx.x >> 2;
    int c16 = (threadIdx.x & 3) * 16;
#pragma unroll
    for (int it = 0; it < 5; ++it) {
      int kk = it * 64 + krow0;
      const unsigned short* wp = (const unsigned short*)W + (long)kk * QD + n_in + c16;
#pragma unroll
      for (int j4 = 0; j4 < 4; ++j4) {
        ushort4 u4 = *(const ushort4*)(wp + j4 * 4);
        lbuf[(c16 + j4 * 4 + 0) * BSTRIDE + kk] = u4.x;
        lbuf[(c16 + j4 * 4 + 1) * BSTRIDE + kk] = u4.y;
        lbuf[(c16 + j4 * 4 + 2) * BSTRIDE + kk] = u4.z;
        lbuf[(c16 + j4 * 4 + 3) * BSTRIDE + kk] = u4.w;
      }
    }
  }
  __syncthreads();
  int wv = threadIdx.x >> 6, lane = threadIdx.x & 63;
  int quad = lane >> 4, li = lane & 15;
  int wm = wv >> 1, wn = wv & 1;
  f32x4 acc[2][2];
#pragma unroll
  for (int a = 0; a < 2; a++)
#pragma unroll
    for (int b = 0; b < 2; b++) acc[a][b] = (f32x4){0.f, 0.f, 0.f, 0.f};
#pragma unroll
  for (int ks = 0; ks < 10; ++ks) {
    short8 af[2], bfrag[2];
#pragma unroll
    for (int mt = 0; mt < 2; ++mt) {
      long r = m0 + wm * 32 + mt * 16 + li;
      if (r > N_TOK - 1) r = N_TOK - 1;
      af[mt] = *(const short8*)(x + r * QD + ks * 32 + quad * 8);
    }
#pragma unroll
    for (int nt = 0; nt < 2; ++nt) {
      int nr = wn * 32 + nt * 16 + li;
      bfrag[nt] = *(const short8*)&lbuf[nr * BSTRIDE + ks * 32 + quad * 8];
    }
#pragma unroll
    for (int mt = 0; mt < 2; ++mt)
#pragma unroll
      for (int nt = 0; nt < 2; ++nt)
        acc[mt][nt] = __builtin_amdgcn_mfma_f32_16x16x32_bf16(af[mt], bfrag[nt], acc[mt][nt], 0, 0, 0);
  }
  __syncthreads();                     // done reading lbuf as B
  unsigned short (*ct)[68] = (unsigned short(*)[68])lbuf;   // alias as C-tile
  const float qs = (wsel == 0) ? 0.15811388300841898f * 1.4426950408889634f : 1.0f;
#pragma unroll
  for (int mt = 0; mt < 2; ++mt)
#pragma unroll
    for (int nt = 0; nt < 2; ++nt)
#pragma unroll
      for (int r = 0; r < 4; ++r)
        ct[wm * 32 + mt * 16 + quad * 4 + r][wn * 32 + nt * 16 + li] =
            bfbits(acc[mt][nt][r] * qs);
  __syncthreads();
  int kt = m0 >> 6;
  if (wsel == 0) {                     // q row-major [h][tok][40]
    int row = threadIdx.x >> 2, c4 = threadIdx.x & 3;
    int grow = m0 + row;
    if (grow < N_TOK) {
#pragma unroll
      for (int i = 0; i < 4; ++i) {
        int cg = c4 + i * 4;           // 4-col chunk; 4|40 -> never crosses a head
        int col = n_in + cg * 4;
        int h = col / DH, d = col % DH;
        ushort4 pk = *(const ushort4*)&ct[row][cg * 4];
        *(ushort4*)(q + (long)h * N_TOK * DH + (long)grow * DH + d) = pk;
      }
    }
  } else if (wsel == 1) {              // K fragment layout (8-d runs never cross 64-col tile)
#pragma unroll
    for (int rep = 0; rep < 2; ++rep) {
      int u = threadIdx.x + rep * 256;
      int row = u >> 3, c8 = (u & 7) * 8;
      int gcol = n_in + c8;
      int h = gcol / DH, d0 = gcol % DH;          // d0 in {0,8,16,24,32}
      int li2 = row & 15, nt2 = row >> 4;
      long base = (((long)h * 65 + kt) * 4 + nt2) * 640 +
                  (d0 < 32 ? ((d0 >> 3) * 16 + li2) * 8 : 512 + li2 * 8);
      ushort4 a = *(const ushort4*)&ct[row][c8];
      ushort4 b = *(const ushort4*)&ct[row][c8 + 4];
      *(ushort4*)(kswz + base) = a;
      *(ushort4*)(kswz + base + 4) = b;
    }
  } else {                             // V fragment layout (8-tok octets, column gather)
#pragma unroll
    for (int rep = 0; rep < 2; ++rep) {
      int u = threadIdx.x + rep * 256;
      int g = u & 7, dcol = u >> 3;
      int gcol = n_in + dcol;
      int h = gcol / DH, d = gcol % DH;
      int dt = d >> 4, li2 = d & 15, ksv = g >> 2, q2 = g & 3;
      union { unsigned short e[8]; ushort4 v[2]; } o;
#pragma unroll
      for (int j = 0; j < 8; ++j) o.e[j] = ct[g * 8 + j][dcol];
      long base = (((long)h * 65 + kt) * 6 + ksv * 3 + dt) * 512 + (q2 * 16 + li2) * 8;
      *(ushort4*)(vswz + base) = o.v[0];
      *(ushort4*)(vswz + base + 4) = o.v[1];
    }
  }
}

// ---------- split-K flash attention: static-max softmax, 32 q-rows/wave,
// 4-wave blocks, single P buffer, SPLITS=8. Proven R0/R7 memory layout.
// Round-9: accumulator-lifetime halving. Occupancy tier = 512/(arch VGPR +
// acc regs) per SIMD; R0-R8 carried s[2][4] (32 acc regs) live across the
// whole ktile -> total >170 -> 2 waves/SIMD (24% occ, the session-long cap).
// Restructured as two independent key-halves per ktile: {QK(nt0,1) -> exp ->
// PV(ksv0)}, {QK(nt2,3) -> exp -> PV(ksv1)} -- only s[2][2] (16) ever live.
// Per-wave totals (loads/MFMAs/exp) unchanged, unlike R5's 16-row split.
// No allocator cap below natural need, unlike R6's spill. ----------
__device__ __forceinline__ void attn_half(
    int kt, int ntb, int dkt, int quad, int li, int lane,
    const short8 (&qa0)[2], const short8 (&qa1)[2],
    const unsigned int (&aw)[2][4], const int (&qi)[2][4],
    const bf16* __restrict__ kb_base, const bf16* __restrict__ vz,
    const unsigned short* __restrict__ bwB,
    f32x4 (&o)[2][3], unsigned short (*pb)[68]) {
  const f32x4 cm8 = (f32x4){-8.f, -8.f, -8.f, -8.f};   // static softmax shift
  f32x4 s[2][2];
  unsigned int bw[2];
#pragma unroll
  for (int nt = 0; nt < 2; ++nt) {
    bw[nt] = bwB[kt * 64 + (ntb + nt) * 16 + li];
    short8 kb0 = *(const short8*)(kb_base + (ntb + nt) * 640 + lane * 8);   // coalesced 1KB
    short8 kb1 = (quad == 0) ? *(const short8*)(kb_base + (ntb + nt) * 640 + 512 + li * 8)
                             : (short8)(__bf16)0.0f;
    s[0][nt] = __builtin_amdgcn_mfma_f32_16x16x32_bf16(qa0[0], kb0, cm8, 0, 0, 0);
    s[0][nt] = __builtin_amdgcn_mfma_f32_16x16x32_bf16(qa1[0], kb1, s[0][nt], 0, 0, 0);
    s[1][nt] = __builtin_amdgcn_mfma_f32_16x16x32_bf16(qa0[1], kb0, cm8, 0, 0, 0);
    s[1][nt] = __builtin_amdgcn_mfma_f32_16x16x32_bf16(qa1[1], kb1, s[1][nt], 0, 0, 0);
  }
  // V fragments for this half (ksv = ntb/2), issued before the exp phase
  short8 vb[3];
#pragma unroll
  for (int dt = 0; dt < 3; ++dt)
    vb[dt] = *(const short8*)(vz + ((long)kt * 6 + (ntb >> 1) * 3 + dt) * 512 + lane * 8);
  // mask -> exp2 (native) -> truncation-pack bf16 -> LDS
  if (kt == dkt) {
#pragma unroll
    for (int mt = 0; mt < 2; ++mt)
#pragma unroll
      for (int nt = 0; nt < 2; ++nt)
#pragma unroll
        for (int r = 0; r < 4; ++r) {
          bool kp = ((aw[mt][r] & bw[nt]) != 0u) ||
                    (qi[mt][r] == (kt * 64 + (ntb + nt) * 16 + li));
          float p = EXP2F(kp ? s[mt][nt][r] : -1e5f);
          pb[mt * 16 + quad * 4 + r][(ntb + nt) * 16 + li] =
              (unsigned short)(__builtin_bit_cast(unsigned int, p) >> 16);
        }
  } else {
#pragma unroll
    for (int mt = 0; mt < 2; ++mt)
#pragma unroll
      for (int nt = 0; nt < 2; ++nt)
#pragma unroll
        for (int r = 0; r < 4; ++r) {
          bool kp = (aw[mt][r] & bw[nt]) != 0u;
          float p = EXP2F(kp ? s[mt][nt][r] : -1e5f);
          pb[mt * 16 + quad * 4 + r][(ntb + nt) * 16 + li] =
              (unsigned short)(__builtin_bit_cast(unsigned int, p) >> 16);
        }
  }
  // PV half: P (A-layout, own wave's LDS region; compiler inserts lgkmcnt) x V.
  // vswz dt=2 col d=40 is all-ones -> o[mt][2] lane li==8 accumulates l for free.
  union { short8 v; ushort4 u[2]; } fp[2];
#pragma unroll
  for (int mt = 0; mt < 2; ++mt) {
    fp[mt].u[0] = *(const ushort4*)&pb[mt * 16 + li][ntb * 16 + quad * 8];
    fp[mt].u[1] = *(const ushort4*)&pb[mt * 16 + li][ntb * 16 + quad * 8 + 4];
  }
#pragma unroll
  for (int dt = 0; dt < 3; ++dt) {
    o[0][dt] = __builtin_amdgcn_mfma_f32_16x16x32_bf16(fp[0].v, vb[dt], o[0][dt], 0, 0, 0);
    o[1][dt] = __builtin_amdgcn_mfma_f32_16x16x32_bf16(fp[1].v, vb[dt], o[1][dt], 0, 0, 0);
  }
}

__global__ __launch_bounds__(256, 3) void attn_kernel(
    const bf16* __restrict__ qg, const bf16* __restrict__ kswz, const bf16* __restrict__ vswz,
    const unsigned short* __restrict__ awA, const unsigned short* __restrict__ bwB,
    float* __restrict__ opart, float* __restrict__ lpart) {
  __shared__ unsigned short pbuf[4][32][68];   // wave, row, col (single buffer)
  int bid = blockIdx.x;
  int h = bid & 7;
  int sp = (bid >> 3) & 7;             // 0..7
  int qt = bid >> 6;                   // 0..32 (128 q-rows per block)
  int kt0 = (sp * 65) >> 3;
  int kt1 = ((sp + 1) * 65) >> 3;
  int wv = threadIdx.x >> 6, lane = threadIdx.x & 63;
  int quad = lane >> 4, li = lane & 15;
  const bf16* qh = qg + h * (N_TOK * DH);
  const bf16* kz = kswz + (long)h * 65 * 2560;
  const bf16* vz = vswz + (long)h * 65 * 3072;

  int qrow_base = qt * 128 + wv * 32;  // up to 4223 < N_SP (awA padded)
  short8 qa0[2], qa1[2];
  unsigned int aw[2][4]; int qi[2][4];
#pragma unroll
  for (int mt = 0; mt < 2; ++mt) {
    int qr = qrow_base + mt * 16 + li; if (qr > N_TOK - 1) qr = N_TOK - 1;
    qa0[mt] = *(const short8*)(qh + qr * DH + quad * 8);
    qa1[mt] = (quad == 0) ? *(const short8*)(qh + qr * DH + 32) : (short8)(__bf16)0.0f;
#pragma unroll
    for (int r = 0; r < 4; ++r) {
      qi[mt][r] = qrow_base + mt * 16 + quad * 4 + r;
      aw[mt][r] = awA[qi[mt][r]];      // padded rows -> 0 -> fully masked -> o=l=0
    }
  }

  f32x4 o[2][3];
#pragma unroll
  for (int mt = 0; mt < 2; ++mt)
#pragma unroll
    for (int d = 0; d < 3; ++d) o[mt][d] = (f32x4){0.f, 0.f, 0.f, 0.f};
  int dkt = qrow_base >> 6;            // the single ktile containing this wave's diagonal

  for (int kt = kt0; kt < kt1; ++kt) {
    const bf16* kb_base = kz + (long)kt * 2560;
    attn_half(kt, 0, dkt, quad, li, lane, qa0, qa1, aw, qi, kb_base, vz, bwB, o, pbuf[wv]);
    attn_half(kt, 2, dkt, quad, li, lane, qa0, qa1, aw, qi, kb_base, vz, bwB, o, pbuf[wv]);
  }

  long pb2 = (long)(sp * 8 + h) * PROWS;
#pragma unroll
  for (int mt = 0; mt < 2; ++mt) {
#pragma unroll
    for (int dt = 0; dt < 3; ++dt) {
      int d = dt * 16 + li;
      if (d < DH) {
#pragma unroll
        for (int r = 0; r < 4; ++r)
          if (qi[mt][r] < PROWS) opart[(pb2 + qi[mt][r]) * DH + d] = o[mt][dt][r];
      }
    }
    if (li == 8) {
#pragma unroll
      for (int r = 0; r < 4; ++r)
        if (qi[mt][r] < PROWS) lpart[pb2 + qi[mt][r]] = o[mt][2][r];
    }
  }
}

// ---------- combine partials across splits (equal weights), float4-vectorized ----------
__global__ __launch_bounds__(256) void combine_kernel(
    const float* __restrict__ opart, const float* __restrict__ lpart,
    bf16* __restrict__ attn) {
  int id = blockIdx.x * 256 + threadIdx.x;   // (h, row, d4): 8*4128*10
  if (id >= 8 * N_TOK * 10) return;
  int d4 = id % 10;
  int rw = (id / 10) % N_TOK;
  int h = id / (10 * N_TOK);
  float4 osum = make_float4(0.f, 0.f, 0.f, 0.f);
  float lsum = 0.f;
#pragma unroll
  for (int s = 0; s < SPLITS; ++s) {
    long rb = (long)(s * 8 + h) * PROWS + rw;
    float4 ov = *(const float4*)(opart + rb * DH + d4 * 4);
    osum.x += ov.x; osum.y += ov.y; osum.z += ov.z; osum.w += ov.w;
    lsum += lpart[rb];
  }
  float rl = 1.0f / fmaxf(lsum, 1e-30f);
  union { short4 s4; unsigned short hh[4]; } u;
  u.hh[0] = bfbits(osum.x * rl); u.hh[1] = bfbits(osum.y * rl);
  u.hh[2] = bfbits(osum.z * rl); u.hh[3] = bfbits(osum.w * rl);
  *(short4*)(attn + rw * QD + h * DH + d4 * 4) = u.s4;
}

// ---------- output projection + bias (pure-bf16 staging; out dtype via sniff) ----------
__global__ __launch_bounds__(256) void gemm_out(
    const bf16* __restrict__ A, const bf16* __restrict__ Wo,
    const float* __restrict__ bias, const void* __restrict__ att,
    void* __restrict__ out) {
  bool isbf = blk_sniff((const unsigned short*)att, 256);
  __shared__ unsigned short lbuf[64 * BSTRIDE];
  int m0 = blockIdx.x * 64;
  int n0 = blockIdx.y * 64;
  {
    int krow0 = threadIdx.x >> 2;
    int c16 = (threadIdx.x & 3) * 16;
#pragma unroll
    for (int it = 0; it < 5; ++it) {
      int kk = it * 64 + krow0;
      const unsigned short* wp = (const unsigned short*)Wo + (long)kk * QD + n0 + c16;
#pragma unroll
      for (int j4 = 0; j4 < 4; ++j4) {
        ushort4 u4 = *(const ushort4*)(wp + j4 * 4);
        lbuf[(c16 + j4 * 4 + 0) * BSTRIDE + kk] = u4.x;
        lbuf[(c16 + j4 * 4 + 1) * BSTRIDE + kk] = u4.y;
        lbuf[(c16 + j4 * 4 + 2) * BSTRIDE + kk] = u4.z;
        lbuf[(c16 + j4 * 4 + 3) * BSTRIDE + kk] = u4.w;
      }
    }
  }
  __syncthreads();
  int wv = threadIdx.x >> 6, lane = threadIdx.x & 63;
  int quad = lane >> 4, li = lane & 15;
  int wm = wv >> 1, wn = wv & 1;
  f32x4 acc[2][2];
#pragma unroll
  for (int a = 0; a < 2; a++)
#pragma unroll
    for (int b = 0; b < 2; b++) acc[a][b] = (f32x4){0.f, 0.f, 0.f, 0.f};
#pragma unroll
  for (int ks = 0; ks < 10; ++ks) {
    short8 af[2], bfrag[2];
#pragma unroll
    for (int mt = 0; mt < 2; ++mt) {
      int r = m0 + wm * 32 + mt * 16 + li;
      r = r < N_TOK ? r : N_TOK - 1;
      af[mt] = *(const short8*)(A + r * QD + ks * 32 + quad * 8);
    }
#pragma unroll
    for (int nt = 0; nt < 2; ++nt) {
      int nr = wn * 32 + nt * 16 + li;
      bfrag[nt] = *(const short8*)&lbuf[nr * BSTRIDE + ks * 32 + quad * 8];
    }
#pragma unroll
    for (int mt = 0; mt < 2; ++mt)
#pragma unroll
      for (int nt = 0; nt < 2; ++nt)
        acc[mt][nt] = __builtin_amdgcn_mfma_f32_16x16x32_bf16(af[mt], bfrag[nt], acc[mt][nt], 0, 0, 0);
  }
#pragma unroll
  for (int mt = 0; mt < 2; ++mt)
#pragma unroll
    for (int nt = 0; nt < 2; ++nt)
#pragma unroll
      for (int r = 0; r < 4; ++r) {
        int row = m0 + wm * 32 + mt * 16 + quad * 4 + r;
        if (row >= N_TOK) continue;
        int col = n0 + wn * 32 + nt * 16 + li;
        float val = acc[mt][nt][r] + bias[col];
        if (isbf) ((bf16*)out)[row * QD + col] = (bf16)val;
        else      ((float*)out)[row * QD + col] = val;
      }
}

extern "C" void kernel_launch(void* const* d_in, const int* in_sizes, int n_in,
                              void* d_out, int out_size, void* d_ws, size_t ws_size,
                              hipStream_t stream) {
  (void)in_sizes; (void)n_in; (void)out_size; (void)ws_size;
  const void* x   = d_in[0];
  const void* att = d_in[1];
  const void* Wq  = d_in[2];
  const void* Wk  = d_in[3];
  const void* Wv  = d_in[4];
  const void* Wo  = d_in[5];
  const void* bo  = d_in[6];
  char* ws = (char*)d_ws;
  unsigned short* awA = (unsigned short*)(ws + 0);        // 8448
  unsigned short* bwB = (unsigned short*)(ws + 8704);     // 8448
  bf16* qb    = (bf16*)(ws + 17408);                      // 2641920
  bf16* kswz  = (bf16*)(ws + 2659328);                    // 2662400
  bf16* vswz  = (bf16*)(ws + 5321728);                    // 3194880
  bf16* attnb = (bf16*)(ws + 8516608);                    // 2641920
  float* opart = (float*)(ws + 11158528);                 // 64*4160*40*4 = 42598400
  float* lpart = (float*)(ws + 53756928);                 // 64*4160*4 = 1064960 -> 54821888
  bf16* wob   = (bf16*)(ws + 54821888);                   // 204800 -> 55026688
  float* bof  = (float*)(ws + 55026688);                  // 1280 -> 55027968 (< old 55493632 peak)
  // xb/wq/wk/wv overlap opart (dead before attn_kernel writes opart):
  bf16* xb    = (bf16*)(ws + 11158528);                   // 2641920
  bf16* wqb   = (bf16*)(ws + 13800448);                   // 204800
  bf16* wkb   = (bf16*)(ws + 14005248);                   // 204800
  bf16* wvb   = (bf16*)(ws + 14210048);                   // 204800 -> 14414848

  cvt_kernel<<<(XCH + 4*WCH + 40 + 255) / 256, 256, 0, stream>>>(
      x, Wq, Wk, Wv, Wo, bo, att, xb, wqb, wkb, wvb, wob, bof);
  dim3 g1(65, 16);   // by 0..14 = GEMM tiles, by 15 = masks + vswz ones
  qkv_mega<<<g1, 256, 0, stream>>>(xb, att, wqb, wkb, wvb, qb, kswz, vswz, awA, bwB);
  attn_kernel<<<33 * SPLITS * 8, 256, 0, stream>>>(qb, kswz, vswz, awA, bwB, opart, lpart);
  combine_kernel<<<(8 * N_TOK * 10 + 255) / 256, 256, 0, stream>>>(opart, lpart, attnb);
  dim3 g2(65, 5);
  gemm_out<<<g2, 256, 0, stream>>>(attnb, wob, bof, att, d_out);
}

// Round 10
// 156.346 us; speedup vs baseline: 1.0376x; 1.0008x over previous
//
#include <hip/hip_runtime.h>

typedef __bf16 bf16;
using short8 = __attribute__((ext_vector_type(8))) __bf16;
using f32x4  = __attribute__((ext_vector_type(4))) float;

#define N_TOK 4128
#define QD    320
#define DH    40
#define W_VIS 4096
#define SPLITS 8
#define N_SP  4224
#define PROWS 4160    /* opart rows per (split,head); rows >=4160 are pure pad, skipped */
#define BSTRIDE 344   /* LDS B-stage stride: 16B-aligned rows, 2-way (free) frag reads */

#if __has_builtin(__builtin_amdgcn_exp2f)
#define EXP2F(x) __builtin_amdgcn_exp2f(x)
#else
#define EXP2F(x) exp2f(x)
#endif

__device__ __forceinline__ float loadS(const void* b, long i, bool isbf) {
  return isbf ? (float)((const bf16*)b)[i] : ((const float*)b)[i];
}
__device__ __forceinline__ unsigned short bfbits(float x) {
  bf16 h = (bf16)x;
  return __builtin_bit_cast(unsigned short, h);
}

// per-block dtype sniff: att is {0,1}; as fp32 its even halfwords are all 0;
// as bf16 ~15% are 0x3F80. 256 samples -> P(miss) ~ 0.85^256 ~ 4e-19.
__device__ __forceinline__ bool blk_sniff(const unsigned short* att_h, int nthr) {
  __shared__ int s;
  if (threadIdx.x == 0) s = 0;
  __syncthreads();
  int step = 8192 / nthr;
  if (att_h[threadIdx.x * step] != 0) atomicOr(&s, 1);
  __syncthreads();
  return s != 0;
}

// ---------- one-shot dtype normalization: x,Wq,Wk,Wv,Wo -> bf16; bo -> f32.
// Removes ALL per-use fp32->bf16 conversion VALU from the GEMM hot loops. ----------
#define XCH  165120   /* 4128*320/8 */
#define WCH  12800    /* 320*320/8 */
__global__ __launch_bounds__(256) void cvt_kernel(
    const void* __restrict__ x, const void* __restrict__ Wq, const void* __restrict__ Wk,
    const void* __restrict__ Wv, const void* __restrict__ Wo, const void* __restrict__ bo,
    const void* __restrict__ att,
    bf16* __restrict__ xb, bf16* __restrict__ wqb, bf16* __restrict__ wkb,
    bf16* __restrict__ wvb, bf16* __restrict__ wob, float* __restrict__ bof) {
  bool isbf = blk_sniff((const unsigned short*)att, 256);
  int c = blockIdx.x * 256 + threadIdx.x;
  const void* src; bf16* dst; long off;
  if (c < XCH)               { src = x;  dst = xb;  off = c; }
  else if (c < XCH + WCH)    { src = Wq; dst = wqb; off = c - XCH; }
  else if (c < XCH + 2*WCH)  { src = Wk; dst = wkb; off = c - XCH - WCH; }
  else if (c < XCH + 3*WCH)  { src = Wv; dst = wvb; off = c - XCH - 2*WCH; }
  else if (c < XCH + 4*WCH)  { src = Wo; dst = wob; off = c - XCH - 3*WCH; }
  else if (c < XCH + 4*WCH + 40) {
    long o = (long)(c - XCH - 4*WCH) * 8;
#pragma unroll
    for (int j = 0; j < 8; ++j) bof[o + j] = loadS(bo, o + j, isbf);
    return;
  } else return;
  long e = off * 8;
  if (isbf) {
    *(short8*)(dst + e) = *(const short8*)((const bf16*)src + e);
  } else {
    const float* f = (const float*)src + e;
    float4 a = *(const float4*)f, b4 = *(const float4*)(f + 4);
    union { short8 v; unsigned short u[8]; } u;
    u.u[0] = bfbits(a.x);  u.u[1] = bfbits(a.y);  u.u[2] = bfbits(a.z);  u.u[3] = bfbits(a.w);
    u.u[4] = bfbits(b4.x); u.u[5] = bfbits(b4.y); u.u[6] = bfbits(b4.z); u.u[7] = bfbits(b4.w);
    *(short8*)(dst + e) = u.v;
  }
}

// ---------- mega QKV: masks+ones (by==15) | pure-bf16 GEMM with LDS-staged B,
// epilogue writes q row-major + kswz/vswz fragment layouts straight from LDS C ----------
__global__ __launch_bounds__(256) void qkv_mega(
    const bf16* __restrict__ x, const void* __restrict__ att,
    const bf16* __restrict__ Wq, const bf16* __restrict__ Wk, const bf16* __restrict__ Wv,
    bf16* __restrict__ q, bf16* __restrict__ kswz, bf16* __restrict__ vswz,
    unsigned short* __restrict__ awA, unsigned short* __restrict__ bwB) {
  bool isbf = blk_sniff((const unsigned short*)att, 256);
  if (blockIdx.y == 15) {      // ---- util slice: mask words + vswz d=40..47 ones/zeros
    int flat = blockIdx.x * 256 + threadIdx.x;
    if (flat < N_SP) {
      int t = flat;
      unsigned int Aw = 0u, Bw = 0u;
      if (t < N_TOK) {
        unsigned int b9 = 0u; bool forced = false;
        if (t < W_VIS) {
#pragma unroll
          for (int o = 0; o < 8; ++o)
            if (loadS(att, o * W_VIS + t, isbf) != 0.0f) b9 |= (1u << o);
        } else {
          int g = t - W_VIS;
          int rep = g >> 3, oo = g & 7;
          forced = (rep == 1 || rep == 2);
          b9 = 0x100u | (forced ? 0u : (1u << oo));
        }
        Aw = b9 | (forced ? 0x200u : 0u) | 0x400u;
        Bw = b9 | (forced ? 0x400u : 0u) | 0x200u;
      }
      awA[t] = (unsigned short)Aw;
      bwB[t] = (unsigned short)Bw;
    } else if (flat - N_SP < 8320) {
      int idx = flat - N_SP;
#pragma unroll
      for (int m = 0; m < 4; ++m) {
        int t = idx * 4 + m;           // 0..33279
        int li8 = t & 7; int t2 = t >> 3;
        int q2 = t2 & 3; t2 >>= 2;
        int ksv = t2 & 1; t2 >>= 1;
        int kt = t2 % 65, h = t2 / 65;
        bf16 val = (li8 == 0) ? (bf16)1.0f : (bf16)0.0f;   // d=40 ones (l via MFMA)
        short8 v8 = {val, val, val, val, val, val, val, val};
        long base = (((long)h * 65 + kt) * 6 + ksv * 3 + 2) * 512;
        *(short8*)(vswz + base + (q2 * 16 + 8 + li8) * 8) = v8;
      }
    }
    return;
  }
  __shared__ unsigned short lbuf[64 * BSTRIDE];   // B-stage; aliased as C-tile later
  int m0 = blockIdx.x * 64;
  int ng = blockIdx.y * 64;
  int wsel = ng / 320;                 // 0=q 1=k 2=v
  int n_in = ng % 320;
  const bf16* W = wsel == 0 ? Wq : wsel == 1 ? Wk : Wv;
  // ---- stage B: W[k][n] -> lbuf[n_rel][k] (coalesced ushort4 reads, b16 transpose)
  {
    int krow0 = threadIdx.x >> 2;
    int c16 = (threadIdx.x & 3) * 16;
#pragma unroll
    for (int it = 0; it < 5; ++it) {
      int kk = it * 64 + krow0;
      const unsigned short* wp = (const unsigned short*)W + (long)kk * QD + n_in + c16;
#pragma unroll
      for (int j4 = 0; j4 < 4; ++j4) {
        ushort4 u4 = *(const ushort4*)(wp + j4 * 4);
        lbuf[(c16 + j4 * 4 + 0) * BSTRIDE + kk] = u4.x;
        lbuf[(c16 + j4 * 4 + 1) * BSTRIDE + kk] = u4.y;
        lbuf[(c16 + j4 * 4 + 2) * BSTRIDE + kk] = u4.z;
        lbuf[(c16 + j4 * 4 + 3) * BSTRIDE + kk] = u4.w;
      }
    }
  }
  __syncthreads();
  int wv = threadIdx.x >> 6, lane = threadIdx.x & 63;
  int quad = lane >> 4, li = lane & 15;
  int wm = wv >> 1, wn = wv & 1;
  f32x4 acc[2][2];
#pragma unroll
  for (int a = 0; a < 2; a++)
#pragma unroll
    for (int b = 0; b < 2; b++) acc[a][b] = (f32x4){0.f, 0.f, 0.f, 0.f};
#pragma unroll
  for (int ks = 0; ks < 10; ++ks) {
    short8 af[2], bfrag[2];
#pragma unroll
    for (int mt = 0; mt < 2; ++mt) {
      long r = m0 + wm * 32 + mt * 16 + li;
      if (r > N_TOK - 1) r = N_TOK - 1;
      af[mt] = *(const short8*)(x + r * QD + ks * 32 + quad * 8);
    }
#pragma unroll
    for (int nt = 0; nt < 2; ++nt) {
      int nr = wn * 32 + nt * 16 + li;
      bfrag[nt] = *(const short8*)&lbuf[nr * BSTRIDE + ks * 32 + quad * 8];
    }
#pragma unroll
    for (int mt = 0; mt < 2; ++mt)
#pragma unroll
      for (int nt = 0; nt < 2; ++nt)
        acc[mt][nt] = __builtin_amdgcn_mfma_f32_16x16x32_bf16(af[mt], bfrag[nt], acc[mt][nt], 0, 0, 0);
  }
  __syncthreads();                     // done reading lbuf as B
  unsigned short (*ct)[68] = (unsigned short(*)[68])lbuf;   // alias as C-tile
  const float qs = (wsel == 0) ? 0.15811388300841898f * 1.4426950408889634f : 1.0f;
#pragma unroll
  for (int mt = 0; mt < 2; ++mt)
#pragma unroll
    for (int nt = 0; nt < 2; ++nt)
#pragma unroll
      for (int r = 0; r < 4; ++r)
        ct[wm * 32 + mt * 16 + quad * 4 + r][wn * 32 + nt * 16 + li] =
            bfbits(acc[mt][nt][r] * qs);
  __syncthreads();
  int kt = m0 >> 6;
  if (wsel == 0) {                     // q row-major [h][tok][40]
    int row = threadIdx.x >> 2, c4 = threadIdx.x & 3;
    int grow = m0 + row;
    if (grow < N_TOK) {
#pragma unroll
      for (int i = 0; i < 4; ++i) {
        int cg = c4 + i * 4;           // 4-col chunk; 4|40 -> never crosses a head
        int col = n_in + cg * 4;
        int h = col / DH, d = col % DH;
        ushort4 pk = *(const ushort4*)&ct[row][cg * 4];
        *(ushort4*)(q + (long)h * N_TOK * DH + (long)grow * DH + d) = pk;
      }
    }
  } else if (wsel == 1) {              // K fragment layout (8-d runs never cross 64-col tile)
#pragma unroll
    for (int rep = 0; rep < 2; ++rep) {
      int u = threadIdx.x + rep * 256;
      int row = u >> 3, c8 = (u & 7) * 8;
      int gcol = n_in + c8;
      int h = gcol / DH, d0 = gcol % DH;          // d0 in {0,8,16,24,32}
      int li2 = row & 15, nt2 = row >> 4;
      long base = (((long)h * 65 + kt) * 4 + nt2) * 640 +
                  (d0 < 32 ? ((d0 >> 3) * 16 + li2) * 8 : 512 + li2 * 8);
      ushort4 a = *(const ushort4*)&ct[row][c8];
      ushort4 b = *(const ushort4*)&ct[row][c8 + 4];
      *(ushort4*)(kswz + base) = a;
      *(ushort4*)(kswz + base + 4) = b;
    }
  } else {                             // V fragment layout (8-tok octets, column gather)
#pragma unroll
    for (int rep = 0; rep < 2; ++rep) {
      int u = threadIdx.x + rep * 256;
      int g = u & 7, dcol = u >> 3;
      int gcol = n_in + dcol;
      int h = gcol / DH, d = gcol % DH;
      int dt = d >> 4, li2 = d & 15, ksv = g >> 2, q2 = g & 3;
      union { unsigned short e[8]; ushort4 v[2]; } o;
#pragma unroll
      for (int j = 0; j < 8; ++j) o.e[j] = ct[g * 8 + j][dcol];
      long base = (((long)h * 65 + kt) * 6 + ksv * 3 + dt) * 512 + (q2 * 16 + li2) * 8;
      *(ushort4*)(vswz + base) = o.v[0];
      *(ushort4*)(vswz + base + 4) = o.v[1];
    }
  }
}

// ---------- split-K flash attention: static-max softmax, 32 q-rows/wave,
// 4-wave blocks, single P buffer, SPLITS=8. Proven R0/R7 memory layout.
// R9 (confirmed +9%): two independent key-halves per ktile so only s[2][2]
// (16 acc regs) is ever live -> arch VGPR 76->60, occupancy 24->29%.
// Round-10: launch_bounds min-waves 3->4. Natural need is now ~100-116 total
// (60 arch + o[24] + transient s[16]) -- BELOW the 128 cap, so unlike R6
// (natural ~144 vs cap 128 -> spill) this should just discipline the
// allocator into the 4-waves/SIMD tier. Abort signature: FETCH/WRITE
// inflation (spill) -> revert to (256,3). ----------
__device__ __forceinline__ void attn_half(
    int kt, int ntb, int dkt, int quad, int li, int lane,
    const short8 (&qa0)[2], const short8 (&qa1)[2],
    const unsigned int (&aw)[2][4], const int (&qi)[2][4],
    const bf16* __restrict__ kb_base, const bf16* __restrict__ vz,
    const unsigned short* __restrict__ bwB,
    f32x4 (&o)[2][3], unsigned short (*pb)[68]) {
  const f32x4 cm8 = (f32x4){-8.f, -8.f, -8.f, -8.f};   // static softmax shift
  f32x4 s[2][2];
  unsigned int bw[2];
#pragma unroll
  for (int nt = 0; nt < 2; ++nt) {
    bw[nt] = bwB[kt * 64 + (ntb + nt) * 16 + li];
    short8 kb0 = *(const short8*)(kb_base + (ntb + nt) * 640 + lane * 8);   // coalesced 1KB
    short8 kb1 = (quad == 0) ? *(const short8*)(kb_base + (ntb + nt) * 640 + 512 + li * 8)
                             : (short8)(__bf16)0.0f;
    s[0][nt] = __builtin_amdgcn_mfma_f32_16x16x32_bf16(qa0[0], kb0, cm8, 0, 0, 0);
    s[0][nt] = __builtin_amdgcn_mfma_f32_16x16x32_bf16(qa1[0], kb1, s[0][nt], 0, 0, 0);
    s[1][nt] = __builtin_amdgcn_mfma_f32_16x16x32_bf16(qa0[1], kb0, cm8, 0, 0, 0);
    s[1][nt] = __builtin_amdgcn_mfma_f32_16x16x32_bf16(qa1[1], kb1, s[1][nt], 0, 0, 0);
  }
  // V fragments for this half (ksv = ntb/2), issued before the exp phase
  short8 vb[3];
#pragma unroll
  for (int dt = 0; dt < 3; ++dt)
    vb[dt] = *(const short8*)(vz + ((long)kt * 6 + (ntb >> 1) * 3 + dt) * 512 + lane * 8);
  // mask -> exp2 (native) -> truncation-pack bf16 -> LDS
  if (kt == dkt) {
#pragma unroll
    for (int mt = 0; mt < 2; ++mt)
#pragma unroll
      for (int nt = 0; nt < 2; ++nt)
#pragma unroll
        for (int r = 0; r < 4; ++r) {
          bool kp = ((aw[mt][r] & bw[nt]) != 0u) ||
                    (qi[mt][r] == (kt * 64 + (ntb + nt) * 16 + li));
          float p = EXP2F(kp ? s[mt][nt][r] : -1e5f);
          pb[mt * 16 + quad * 4 + r][(ntb + nt) * 16 + li] =
              (unsigned short)(__builtin_bit_cast(unsigned int, p) >> 16);
        }
  } else {
#pragma unroll
    for (int mt = 0; mt < 2; ++mt)
#pragma unroll
      for (int nt = 0; nt < 2; ++nt)
#pragma unroll
        for (int r = 0; r < 4; ++r) {
          bool kp = (aw[mt][r] & bw[nt]) != 0u;
          float p = EXP2F(kp ? s[mt][nt][r] : -1e5f);
          pb[mt * 16 + quad * 4 + r][(ntb + nt) * 16 + li] =
              (unsigned short)(__builtin_bit_cast(unsigned int, p) >> 16);
        }
  }
  // PV half: P (A-layout, own wave's LDS region; compiler inserts lgkmcnt) x V.
  // vswz dt=2 col d=40 is all-ones -> o[mt][2] lane li==8 accumulates l for free.
  union { short8 v; ushort4 u[2]; } fp[2];
#pragma unroll
  for (int mt = 0; mt < 2; ++mt) {
    fp[mt].u[0] = *(const ushort4*)&pb[mt * 16 + li][ntb * 16 + quad * 8];
    fp[mt].u[1] = *(const ushort4*)&pb[mt * 16 + li][ntb * 16 + quad * 8 + 4];
  }
#pragma unroll
  for (int dt = 0; dt < 3; ++dt) {
    o[0][dt] = __builtin_amdgcn_mfma_f32_16x16x32_bf16(fp[0].v, vb[dt], o[0][dt], 0, 0, 0);
    o[1][dt] = __builtin_amdgcn_mfma_f32_16x16x32_bf16(fp[1].v, vb[dt], o[1][dt], 0, 0, 0);
  }
}

__global__ __launch_bounds__(256, 4) void attn_kernel(
    const bf16* __restrict__ qg, const bf16* __restrict__ kswz, const bf16* __restrict__ vswz,
    const unsigned short* __restrict__ awA, const unsigned short* __restrict__ bwB,
    float* __restrict__ opart, float* __restrict__ lpart) {
  __shared__ unsigned short pbuf[4][32][68];   // wave, row, col (single buffer)
  int bid = blockIdx.x;
  int h = bid & 7;
  int sp = (bid >> 3) & 7;             // 0..7
  int qt = bid >> 6;                   // 0..32 (128 q-rows per block)
  int kt0 = (sp * 65) >> 3;
  int kt1 = ((sp + 1) * 65) >> 3;
  int wv = threadIdx.x >> 6, lane = threadIdx.x & 63;
  int quad = lane >> 4, li = lane & 15;
  const bf16* qh = qg + h * (N_TOK * DH);
  const bf16* kz = kswz + (long)h * 65 * 2560;
  const bf16* vz = vswz + (long)h * 65 * 3072;

  int qrow_base = qt * 128 + wv * 32;  // up to 4223 < N_SP (awA padded)
  short8 qa0[2], qa1[2];
  unsigned int aw[2][4]; int qi[2][4];
#pragma unroll
  for (int mt = 0; mt < 2; ++mt) {
    int qr = qrow_base + mt * 16 + li; if (qr > N_TOK - 1) qr = N_TOK - 1;
    qa0[mt] = *(const short8*)(qh + qr * DH + quad * 8);
    qa1[mt] = (quad == 0) ? *(const short8*)(qh + qr * DH + 32) : (short8)(__bf16)0.0f;
#pragma unroll
    for (int r = 0; r < 4; ++r) {
      qi[mt][r] = qrow_base + mt * 16 + quad * 4 + r;
      aw[mt][r] = awA[qi[mt][r]];      // padded rows -> 0 -> fully masked -> o=l=0
    }
  }

  f32x4 o[2][3];
#pragma unroll
  for (int mt = 0; mt < 2; ++mt)
#pragma unroll
    for (int d = 0; d < 3; ++d) o[mt][d] = (f32x4){0.f, 0.f, 0.f, 0.f};
  int dkt = qrow_base >> 6;            // the single ktile containing this wave's diagonal

  for (int kt = kt0; kt < kt1; ++kt) {
    const bf16* kb_base = kz + (long)kt * 2560;
    attn_half(kt, 0, dkt, quad, li, lane, qa0, qa1, aw, qi, kb_base, vz, bwB, o, pbuf[wv]);
    attn_half(kt, 2, dkt, quad, li, lane, qa0, qa1, aw, qi, kb_base, vz, bwB, o, pbuf[wv]);
  }

  long pb2 = (long)(sp * 8 + h) * PROWS;
#pragma unroll
  for (int mt = 0; mt < 2; ++mt) {
#pragma unroll
    for (int dt = 0; dt < 3; ++dt) {
      int d = dt * 16 + li;
      if (d < DH) {
#pragma unroll
        for (int r = 0; r < 4; ++r)
          if (qi[mt][r] < PROWS) opart[(pb2 + qi[mt][r]) * DH + d] = o[mt][dt][r];
      }
    }
    if (li == 8) {
#pragma unroll
      for (int r = 0; r < 4; ++r)
        if (qi[mt][r] < PROWS) lpart[pb2 + qi[mt][r]] = o[mt][2][r];
    }
  }
}

// ---------- combine partials across splits (equal weights), float4-vectorized ----------
__global__ __launch_bounds__(256) void combine_kernel(
    const float* __restrict__ opart, const float* __restrict__ lpart,
    bf16* __restrict__ attn) {
  int id = blockIdx.x * 256 + threadIdx.x;   // (h, row, d4): 8*4128*10
  if (id >= 8 * N_TOK * 10) return;
  int d4 = id % 10;
  int rw = (id / 10) % N_TOK;
  int h = id / (10 * N_TOK);
  float4 osum = make_float4(0.f, 0.f, 0.f, 0.f);
  float lsum = 0.f;
#pragma unroll
  for (int s = 0; s < SPLITS; ++s) {
    long rb = (long)(s * 8 + h) * PROWS + rw;
    float4 ov = *(const float4*)(opart + rb * DH + d4 * 4);
    osum.x += ov.x; osum.y += ov.y; osum.z += ov.z; osum.w += ov.w;
    lsum += lpart[rb];
  }
  float rl = 1.0f / fmaxf(lsum, 1e-30f);
  union { short4 s4; unsigned short hh[4]; } u;
  u.hh[0] = bfbits(osum.x * rl); u.hh[1] = bfbits(osum.y * rl);
  u.hh[2] = bfbits(osum.z * rl); u.hh[3] = bfbits(osum.w * rl);
  *(short4*)(attn + rw * QD + h * DH + d4 * 4) = u.s4;
}

// ---------- output projection + bias (pure-bf16 staging; out dtype via sniff) ----------
__global__ __launch_bounds__(256) void gemm_out(
    const bf16* __restrict__ A, const bf16* __restrict__ Wo,
    const float* __restrict__ bias, const void* __restrict__ att,
    void* __restrict__ out) {
  bool isbf = blk_sniff((const unsigned short*)att, 256);
  __shared__ unsigned short lbuf[64 * BSTRIDE];
  int m0 = blockIdx.x * 64;
  int n0 = blockIdx.y * 64;
  {
    int krow0 = threadIdx.x >> 2;
    int c16 = (threadIdx.x & 3) * 16;
#pragma unroll
    for (int it = 0; it < 5; ++it) {
      int kk = it * 64 + krow0;
      const unsigned short* wp = (const unsigned short*)Wo + (long)kk * QD + n0 + c16;
#pragma unroll
      for (int j4 = 0; j4 < 4; ++j4) {
        ushort4 u4 = *(const ushort4*)(wp + j4 * 4);
        lbuf[(c16 + j4 * 4 + 0) * BSTRIDE + kk] = u4.x;
        lbuf[(c16 + j4 * 4 + 1) * BSTRIDE + kk] = u4.y;
        lbuf[(c16 + j4 * 4 + 2) * BSTRIDE + kk] = u4.z;
        lbuf[(c16 + j4 * 4 + 3) * BSTRIDE + kk] = u4.w;
      }
    }
  }
  __syncthreads();
  int wv = threadIdx.x >> 6, lane = threadIdx.x & 63;
  int quad = lane >> 4, li = lane & 15;
  int wm = wv >> 1, wn = wv & 1;
  f32x4 acc[2][2];
#pragma unroll
  for (int a = 0; a < 2; a++)
#pragma unroll
    for (int b = 0; b < 2; b++) acc[a][b] = (f32x4){0.f, 0.f, 0.f, 0.f};
#pragma unroll
  for (int ks = 0; ks < 10; ++ks) {
    short8 af[2], bfrag[2];
#pragma unroll
    for (int mt = 0; mt < 2; ++mt) {
      int r = m0 + wm * 32 + mt * 16 + li;
      r = r < N_TOK ? r : N_TOK - 1;
      af[mt] = *(const short8*)(A + r * QD + ks * 32 + quad * 8);
    }
#pragma unroll
    for (int nt = 0; nt < 2; ++nt) {
      int nr = wn * 32 + nt * 16 + li;
      bfrag[nt] = *(const short8*)&lbuf[nr * BSTRIDE + ks * 32 + quad * 8];
    }
#pragma unroll
    for (int mt = 0; mt < 2; ++mt)
#pragma unroll
      for (int nt = 0; nt < 2; ++nt)
        acc[mt][nt] = __builtin_amdgcn_mfma_f32_16x16x32_bf16(af[mt], bfrag[nt], acc[mt][nt], 0, 0, 0);
  }
#pragma unroll
  for (int mt = 0; mt < 2; ++mt)
#pragma unroll
    for (int nt = 0; nt < 2; ++nt)
#pragma unroll
      for (int r = 0; r < 4; ++r) {
        int row = m0 + wm * 32 + mt * 16 + quad * 4 + r;
        if (row >= N_TOK) continue;
        int col = n0 + wn * 32 + nt * 16 + li;
        float val = acc[mt][nt][r] + bias[col];
        if (isbf) ((bf16*)out)[row * QD + col] = (bf16)val;
        else      ((float*)out)[row * QD + col] = val;
      }
}

extern "C" void kernel_launch(void* const* d_in, const int* in_sizes, int n_in,
                              void* d_out, int out_size, void* d_ws, size_t ws_size,
                              hipStream_t stream) {
  (void)in_sizes; (void)n_in; (void)out_size; (void)ws_size;
  const void* x   = d_in[0];
  const void* att = d_in[1];
  const void* Wq  = d_in[2];
  const void* Wk  = d_in[3];
  const void* Wv  = d_in[4];
  const void* Wo  = d_in[5];
  const void* bo  = d_in[6];
  char* ws = (char*)d_ws;
  unsigned short* awA = (unsigned short*)(ws + 0);        // 8448
  unsigned short* bwB = (unsigned short*)(ws + 8704);     // 8448
  bf16* qb    = (bf16*)(ws + 17408);                      // 2641920
  bf16* kswz  = (bf16*)(ws + 2659328);                    // 2662400
  bf16* vswz  = (bf16*)(ws + 5321728);                    // 3194880
  bf16* attnb = (bf16*)(ws + 8516608);                    // 2641920
  float* opart = (float*)(ws + 11158528);                 // 64*4160*40*4 = 42598400
  float* lpart = (float*)(ws + 53756928);                 // 64*4160*4 = 1064960 -> 54821888
  bf16* wob   = (bf16*)(ws + 54821888);                   // 204800 -> 55026688
  float* bof  = (float*)(ws + 55026688);                  // 1280 -> 55027968 (< old 55493632 peak)
  // xb/wq/wk/wv overlap opart (dead before attn_kernel writes opart):
  bf16* xb    = (bf16*)(ws + 11158528);                   // 2641920
  bf16* wqb   = (bf16*)(ws + 13800448);                   // 204800
  bf16* wkb   = (bf16*)(ws + 14005248);                   // 204800
  bf16* wvb   = (bf16*)(ws + 14210048);                   // 204800 -> 14414848

  cvt_kernel<<<(XCH + 4*WCH + 40 + 255) / 256, 256, 0, stream>>>(
      x, Wq, Wk, Wv, Wo, bo, att, xb, wqb, wkb, wvb, wob, bof);
  dim3 g1(65, 16);   // by 0..14 = GEMM tiles, by 15 = masks + vswz ones
  qkv_mega<<<g1, 256, 0, stream>>>(xb, att, wqb, wkb, wvb, qb, kswz, vswz, awA, bwB);
  attn_kernel<<<33 * SPLITS * 8, 256, 0, stream>>>(qb, kswz, vswz, awA, bwB, opart, lpart);
  combine_kernel<<<(8 * N_TOK * 10 + 255) / 256, 256, 0, stream>>>(opart, lpart, attnb);
  dim3 g2(65, 5);
  gemm_out<<<g2, 256, 0, stream>>>(attnb, wob, bof, att, d_out);
}